// Round 1
// baseline (555.912 us; speedup 1.0000x reference)
//
#include <hip/hip_runtime.h>
#include <hip/hip_bf16.h>
#include <math.h>

typedef short s16x8 __attribute__((ext_vector_type(8)));
typedef float f32x4 __attribute__((ext_vector_type(4)));
typedef unsigned int u32;

#define N_DEST 10000
#define N_SRC  8000
#define IN_DIM 256
#define HID    128
#define MPAD   10240
#define SCALE  0.08838834764831845f   // 1/sqrt(128)
#define LRS    0.2f

// big-kernel tiling
#define BM      256      // rows per WG (4 waves x 64 rows)
#define NCHUNK  320      // cols per WG (5 tiles of 64); 25*320 = 8000 exactly
#define NTILE   64
#define MBLKS   40       // ceil(10000/256), rows padded to 10240
#define NCHUNKS 25

__device__ inline unsigned short f2bf(float f) {
    u32 x = __float_as_uint(f);
    return (unsigned short)((x + 0x7fffu + ((x >> 16) & 1u)) >> 16);  // RNE, no NaN inputs here
}
__device__ inline float bf2f(unsigned short u) { return __uint_as_float(((u32)u) << 16); }

// ---------------- P0: ft NaN-clean + zero accumulators ----------------
__global__ void prep_kernel(const float* __restrict__ ft, float* __restrict__ ftc,
                            float* __restrict__ okf, float* __restrict__ sumb,
                            float* __restrict__ accb) {
    int i = blockIdx.x * 256 + threadIdx.x;
    if (i < MPAD) { sumb[i] = 0.f; accb[i] = 0.f; }
    if (i < N_SRC) {
        float v = ft[i];
        bool n = (v != v);
        ftc[i] = n ? 0.f : v;
        okf[i] = n ? 0.f : 1.f;
    }
}

// ---------------- P1: Wc = (W @ W2) * scale  [256x128] ----------------
__global__ __launch_bounds__(256)
void wc_kernel(const float* __restrict__ W, const float* __restrict__ W2,
               float* __restrict__ Wc) {
    __shared__ float W2s[128][128];
    __shared__ float Wrs[16][128];
    const int t = threadIdx.x;
    // stage W2 (64 KB)
    for (int i = 0; i < 16; ++i) {
        int f = i * 256 + t;            // float4 id, < 4096
        int kk = f >> 5, c = (f & 31) * 4;
        *(float4*)&W2s[kk][c] = *(const float4*)&W2[kk * 128 + c];
    }
    const int a0 = blockIdx.x * 16;
    for (int i = 0; i < 2; ++i) {
        int f = i * 256 + t;            // float4 id, < 512
        int r = f >> 5, c = (f & 31) * 4;
        *(float4*)&Wrs[r][c] = *(const float4*)&W[(a0 + r) * 128 + c];
    }
    __syncthreads();
    const int bq = t & 15, ar = t >> 4;
    float acc[8];
#pragma unroll
    for (int j = 0; j < 8; ++j) acc[j] = 0.f;
    for (int k = 0; k < 128; ++k) {
        float av = Wrs[ar][k];
        float4 w0 = *(float4*)&W2s[k][bq * 8];
        float4 w1 = *(float4*)&W2s[k][bq * 8 + 4];
        acc[0] += av * w0.x; acc[1] += av * w0.y; acc[2] += av * w0.z; acc[3] += av * w0.w;
        acc[4] += av * w1.x; acc[5] += av * w1.y; acc[6] += av * w1.z; acc[7] += av * w1.w;
    }
    float4 o0 = { acc[0] * SCALE, acc[1] * SCALE, acc[2] * SCALE, acc[3] * SCALE };
    float4 o1 = { acc[4] * SCALE, acc[5] * SCALE, acc[6] * SCALE, acc[7] * SCALE };
    *(float4*)&Wc[(a0 + ar) * 128 + bq * 8]     = o0;
    *(float4*)&Wc[(a0 + ar) * 128 + bq * 8 + 4] = o1;
}

// ---------------- P2: C[M x 128] = A[M x 256] @ B[256 x 128], fp32 ----------------
// MODE 0: plain bf16 row-major out (g2 path, pad rows -> 0)
// MODE 1: bf16 hi/lo split row-major out (h1 path)
template<int MODE>
__global__ __launch_bounds__(128)
void proj_kernel(const float* __restrict__ A, const float* __restrict__ Bm, int Mreal,
                 unsigned short* __restrict__ Oh, unsigned short* __restrict__ Ol) {
    __shared__ float As[64][65];     // +1 pad: conflict-free column reads
    __shared__ float Bs[64][128];
    const int t = threadIdx.x;
    const int hq = t & 15, rg = t >> 4;      // hq: h-octet, rg: row group (8 rows)
    const int row0 = blockIdx.x * 64;
    float acc[8][8];
#pragma unroll
    for (int i = 0; i < 8; ++i)
#pragma unroll
        for (int j = 0; j < 8; ++j) acc[i][j] = 0.f;

    for (int q = 0; q < 4; ++q) {            // K quarters of 64
        const int k0 = q * 64;
        __syncthreads();
        for (int i = 0; i < 8; ++i) {        // A tile: 1024 float4s
            int f = i * 128 + t;
            int r = f >> 4, c = (f & 15) * 4;
            int gr = min(row0 + r, Mreal - 1);
            float4 v = *(const float4*)&A[(size_t)gr * IN_DIM + k0 + c];
            As[r][c] = v.x; As[r][c + 1] = v.y; As[r][c + 2] = v.z; As[r][c + 3] = v.w;
        }
        for (int i = 0; i < 16; ++i) {       // B tile: 2048 float4s
            int f = i * 128 + t;
            int r = f >> 5, c = (f & 31) * 4;
            *(float4*)&Bs[r][c] = *(const float4*)&Bm[(k0 + r) * HID + c];
        }
        __syncthreads();
#pragma unroll 4
        for (int k = 0; k < 64; ++k) {
            float4 w0 = *(float4*)&Bs[k][hq * 8];
            float4 w1 = *(float4*)&Bs[k][hq * 8 + 4];
#pragma unroll
            for (int i = 0; i < 8; ++i) {
                float av = As[rg * 8 + i][k];
                acc[i][0] += av * w0.x; acc[i][1] += av * w0.y;
                acc[i][2] += av * w0.z; acc[i][3] += av * w0.w;
                acc[i][4] += av * w1.x; acc[i][5] += av * w1.y;
                acc[i][6] += av * w1.z; acc[i][7] += av * w1.w;
            }
        }
    }
#pragma unroll
    for (int i = 0; i < 8; ++i) {
        const int r = row0 + rg * 8 + i;
        const bool valid = (r < Mreal);
        unsigned short oh[8], ol[8];
#pragma unroll
        for (int j = 0; j < 8; ++j) {
            float x = valid ? acc[i][j] : 0.f;
            unsigned short h = f2bf(x);
            oh[j] = h;
            if (MODE == 1) ol[j] = f2bf(x - bf2f(h));
        }
        *(uint4*)&Oh[(size_t)r * HID + hq * 8] = *(uint4*)oh;
        if (MODE == 1) *(uint4*)&Ol[(size_t)r * HID + hq * 8] = *(uint4*)ol;
    }
}

// ---------------- D: fused e = g2 @ h1^T, lrelu, mask, exp, row partials ----------------
// grid = (NCHUNKS, MBLKS), 256 threads (4 waves). Wave strip: 64 rows x 64 cols/iter.
// A (g2, pre-scaled) plain bf16 in registers; B (h1) hi/lo bf16 in LDS (2-pass MFMA).
// No online max: scores bounded (~|s|<10 after scale), softmax is shift-invariant.
__global__ __launch_bounds__(256, 2)
void attn_kernel(const float* __restrict__ bias, const unsigned short* __restrict__ g2b,
                 const unsigned short* __restrict__ h1h, const unsigned short* __restrict__ h1l,
                 const float* __restrict__ ftc, const float* __restrict__ okf,
                 float* __restrict__ sumb, float* __restrict__ accb) {
    __shared__ char Bsh[2][16384];   // [half][col 64 x 256B swizzled]
    __shared__ float fts[NCHUNK];
    __shared__ float oks[NCHUNK];
    const int t = threadIdx.x;
    const int w = t >> 6, l = t & 63;
    const int m15 = l & 15, g = l >> 4;
    const int chunk = blockIdx.x, mblk = blockIdx.y;
    const int mrow0 = mblk * BM + w * 64;
    const int jc0 = chunk * NCHUNK;

    for (int i = t; i < NCHUNK; i += 256) { fts[i] = ftc[jc0 + i]; oks[i] = okf[jc0 + i]; }

    // A fragments: 16 x (8 bf16), resident for the whole kernel
    s16x8 afr[4][4];
#pragma unroll
    for (int mf = 0; mf < 4; ++mf)
#pragma unroll
        for (int ka = 0; ka < 4; ++ka) {
            const int row = mrow0 + 16 * mf + m15;       // < MPAD (zero-padded)
            afr[mf][ka] = *(const s16x8*)(g2b + (size_t)row * HID + ka * 32 + g * 8);
        }

    // per-lane swizzled k-offsets for B-frag ds_reads
    int tk[4];
#pragma unroll
    for (int ka = 0; ka < 4; ++ka) tk[ka] = ((ka * 64 + g * 16) ^ ((m15 & 7) << 4));

    float ps[16], pa[16];
#pragma unroll
    for (int s = 0; s < 16; ++s) { ps[s] = 0.f; pa[s] = 0.f; }

    for (int it = 0; it < 5; ++it) {
        const int j0 = jc0 + it * NTILE;
        __syncthreads();                     // previous tile fully consumed
        // stage h1 hi/lo tile (64 cols x 128 k), XOR-swizzled at ds_write
#pragma unroll
        for (int i = 0; i < 4; ++i) {
            int id = t + 256 * i;            // 16B-block id, < 1024
            int c = id >> 4, q = id & 15;
            uint4 vh = *(const uint4*)(h1h + (size_t)(j0 + c) * HID + q * 8);
            uint4 vl = *(const uint4*)(h1l + (size_t)(j0 + c) * HID + q * 8);
            int dst = c * 256 + ((q * 16) ^ ((c & 7) << 4));
            *(uint4*)&Bsh[0][dst] = vh;
            *(uint4*)&Bsh[1][dst] = vl;
        }
        __syncthreads();

        // bias loads for the whole iter, issued early (latency hidden under MFMA)
        float bv[4][4][4];
#pragma unroll
        for (int mf = 0; mf < 4; ++mf)
#pragma unroll
            for (int ri = 0; ri < 4; ++ri) {
                int row = mrow0 + 16 * mf + 4 * g + ri;
                row = min(row, N_DEST - 1);              // pad rows read row 9999 (discarded)
                const u32 rb = (u32)row * (u32)N_SRC;
#pragma unroll
                for (int nf = 0; nf < 4; ++nf) {
                    bv[mf][ri][nf] = bias[rb + (u32)(j0 + 16 * nf + m15)];
                }
            }

#pragma unroll
        for (int nf = 0; nf < 4; ++nf) {
            s16x8 bh[4], bl[4];
#pragma unroll
            for (int ka = 0; ka < 4; ++ka) {
                int off = (nf * 16 + m15) * 256 + tk[ka];
                bh[ka] = *(const s16x8*)&Bsh[0][off];
                bl[ka] = *(const s16x8*)&Bsh[1][off];
            }
            const float ftv = fts[it * 64 + nf * 16 + m15];
            const float okv = oks[it * 64 + nf * 16 + m15];
#pragma unroll
            for (int mf = 0; mf < 4; ++mf) {
                f32x4 acc = { 0.f, 0.f, 0.f, 0.f };
#pragma unroll
                for (int ka = 0; ka < 4; ++ka) {
                    acc = __builtin_amdgcn_mfma_f32_16x16x32_bf16(afr[mf][ka], bh[ka], acc, 0, 0, 0);
                    acc = __builtin_amdgcn_mfma_f32_16x16x32_bf16(afr[mf][ka], bl[ka], acc, 0, 0, 0);
                }
#pragma unroll
                for (int ri = 0; ri < 4; ++ri) {
                    float s = acc[ri];
                    s = fmaxf(s, LRS * s);                       // lrelu (scale pre-folded)
                    float keep = (bv[mf][ri][nf] > 0.0f) ? okv : 0.0f;
                    float p = exp2f(s * 1.44269504f) * keep;     // exp(s); masked -> 0
                    ps[mf * 4 + ri] += p;
                    pa[mf * 4 + ri] += p * ftv;
                }
            }
        }
    }

    // reduce each row partial across its 16-lane group, then one atomic per row
#pragma unroll
    for (int s = 0; s < 16; ++s) {
        float a = ps[s], b = pa[s];
#pragma unroll
        for (int m = 1; m < 16; m <<= 1) {
            a += __shfl_xor(a, m, 64);
            b += __shfl_xor(b, m, 64);
        }
        if (m15 == 0) {
            int row = mrow0 + 16 * (s >> 2) + 4 * g + (s & 3);
            if (row < N_DEST) {
                atomicAdd(&sumb[row], a);
                atomicAdd(&accb[row], b);
            }
        }
    }
}

// ---------------- F: out = acc / sum ----------------
__global__ void fin_kernel(const float* __restrict__ sumb, const float* __restrict__ accb,
                           float* __restrict__ out) {
    int i = blockIdx.x * 256 + threadIdx.x;
    if (i < N_DEST) out[i] = accb[i] / sumb[i];
}

extern "C" void kernel_launch(void* const* d_in, const int* in_sizes, int n_in,
                              void* d_out, int out_size, void* d_ws, size_t ws_size,
                              hipStream_t stream) {
    const float* bias     = (const float*)d_in[0];
    const float* emb_dest = (const float*)d_in[1];
    const float* emb_src  = (const float*)d_in[2];
    const float* ftr      = (const float*)d_in[3];
    const float* W        = (const float*)d_in[4];
    const float* W2       = (const float*)d_in[5];
    float* out = (float*)d_out;

    char* ws = (char*)d_ws;
    size_t off = 0;
    auto alloc = [&](size_t bytes) -> void* {
        void* p = ws + off;
        off += (bytes + 255) & ~(size_t)255;
        return p;
    };
    float* Wc           = (float*)alloc(256 * 128 * 4);
    unsigned short* g2b = (unsigned short*)alloc((size_t)MPAD * HID * 2);
    unsigned short* h1h = (unsigned short*)alloc((size_t)N_SRC * HID * 2);
    unsigned short* h1l = (unsigned short*)alloc((size_t)N_SRC * HID * 2);
    float* ftc          = (float*)alloc(N_SRC * 4);
    float* okf          = (float*)alloc(N_SRC * 4);
    float* sumb         = (float*)alloc(MPAD * 4);
    float* accb         = (float*)alloc(MPAD * 4);
    (void)ws_size; (void)in_sizes; (void)n_in; (void)out_size;

    prep_kernel<<<MPAD / 256, 256, 0, stream>>>(ftr, ftc, okf, sumb, accb);
    wc_kernel<<<16, 256, 0, stream>>>(W, W2, Wc);
    proj_kernel<1><<<N_SRC / 64, 128, 0, stream>>>(emb_src, W, N_SRC, h1h, h1l);
    proj_kernel<0><<<MPAD / 64, 128, 0, stream>>>(emb_dest, Wc, N_DEST, g2b, nullptr);
    attn_kernel<<<dim3(NCHUNKS, MBLKS), 256, 0, stream>>>(bias, g2b, h1h, h1l, ftc, okf, sumb, accb);
    fin_kernel<<<MPAD / 256, 256, 0, stream>>>(sumb, accb, out);
}

// Round 3
// 512.232 us; speedup vs baseline: 1.0853x; 1.0853x over previous
//
#include <hip/hip_runtime.h>
#include <hip/hip_bf16.h>
#include <math.h>

typedef short s16x8 __attribute__((ext_vector_type(8)));
typedef float f32x4 __attribute__((ext_vector_type(4)));
typedef unsigned int u32;

#define N_DEST 10000
#define N_SRC  8000
#define IN_DIM 256
#define HID    128
#define MPAD   10240
// SCALE * log2(e): folded into Wc so attn computes p = exp2(lrelu(s)) directly
#define WCC (0.08838834764831845f * 1.4426950408889634f)
#define LRS    0.2f

// big-kernel tiling
#define BM      256      // rows per WG (4 waves x 64 rows)
#define NCHUNK  320      // cols per WG (5 tiles of 64); 25*320 = 8000 exactly
#define NTILE   64
#define MBLKS   40       // ceil(10000/256), rows padded to 10240
#define NCHUNKS 25

__device__ inline unsigned short f2bf(float f) {
    u32 x = __float_as_uint(f);
    return (unsigned short)((x + 0x7fffu + ((x >> 16) & 1u)) >> 16);  // RNE, no NaN inputs here
}
__device__ inline float bf2f(unsigned short u) { return __uint_as_float(((u32)u) << 16); }

// ---------------- P0: ft NaN-clean + zero accumulators ----------------
__global__ void prep_kernel(const float* __restrict__ ft, float* __restrict__ ftc,
                            float* __restrict__ okf, float* __restrict__ sumb,
                            float* __restrict__ accb) {
    int i = blockIdx.x * 256 + threadIdx.x;
    if (i < MPAD) { sumb[i] = 0.f; accb[i] = 0.f; }
    if (i < N_SRC) {
        float v = ft[i];
        bool n = (v != v);
        ftc[i] = n ? 0.f : v;
        okf[i] = n ? 0.f : 1.f;
    }
}

// ---------------- P1: Wc = (W @ W2) * SCALE * log2e  [256x128] ----------------
__global__ __launch_bounds__(256)
void wc_kernel(const float* __restrict__ W, const float* __restrict__ W2,
               float* __restrict__ Wc) {
    __shared__ float W2s[128][128];
    __shared__ float Wrs[16][128];
    const int t = threadIdx.x;
    for (int i = 0; i < 16; ++i) {
        int f = i * 256 + t;            // float4 id, < 4096
        int kk = f >> 5, c = (f & 31) * 4;
        *(float4*)&W2s[kk][c] = *(const float4*)&W2[kk * 128 + c];
    }
    const int a0 = blockIdx.x * 16;
    for (int i = 0; i < 2; ++i) {
        int f = i * 256 + t;            // float4 id, < 512
        int r = f >> 5, c = (f & 31) * 4;
        *(float4*)&Wrs[r][c] = *(const float4*)&W[(a0 + r) * 128 + c];
    }
    __syncthreads();
    const int bq = t & 15, ar = t >> 4;
    float acc[8];
#pragma unroll
    for (int j = 0; j < 8; ++j) acc[j] = 0.f;
    for (int k = 0; k < 128; ++k) {
        float av = Wrs[ar][k];
        float4 w0 = *(float4*)&W2s[k][bq * 8];
        float4 w1 = *(float4*)&W2s[k][bq * 8 + 4];
        acc[0] += av * w0.x; acc[1] += av * w0.y; acc[2] += av * w0.z; acc[3] += av * w0.w;
        acc[4] += av * w1.x; acc[5] += av * w1.y; acc[6] += av * w1.z; acc[7] += av * w1.w;
    }
    float4 o0 = { acc[0] * WCC, acc[1] * WCC, acc[2] * WCC, acc[3] * WCC };
    float4 o1 = { acc[4] * WCC, acc[5] * WCC, acc[6] * WCC, acc[7] * WCC };
    *(float4*)&Wc[(a0 + ar) * 128 + bq * 8]     = o0;
    *(float4*)&Wc[(a0 + ar) * 128 + bq * 8 + 4] = o1;
}

// ---------------- P2: fused projections ----------------
// blocks [0,160): g2 = emb_dest @ Wc -> plain bf16, rows padded to 10240 with 0
// blocks [160,285): h1 = emb_src @ W -> hi/lo bf16 split
// 256 threads; tile 64 rows x 128 cols; thread = 8 rows x 4 cols.
__global__ __launch_bounds__(256)
void proj2_kernel(const float* __restrict__ emb_dest, const float* __restrict__ emb_src,
                  const float* __restrict__ Wc, const float* __restrict__ W,
                  unsigned short* __restrict__ g2b, unsigned short* __restrict__ h1h,
                  unsigned short* __restrict__ h1l) {
    __shared__ float As[64][72];     // pad 72: float4-alignable, row-group reads broadcast
    __shared__ float Bs[64][128];
    const int t = threadIdx.x;
    const int cg = t & 31;           // 32 col-groups x 4 cols
    const int rg = t >> 5;           // 8 row-groups x 8 rows
    const bool dest = (blockIdx.x < 160);
    const int row0 = (dest ? blockIdx.x : (blockIdx.x - 160)) * 64;
    const float* __restrict__ A = dest ? emb_dest : emb_src;
    const float* __restrict__ B = dest ? Wc : W;
    const int Mreal = dest ? N_DEST : N_SRC;

    float acc[8][4];
#pragma unroll
    for (int i = 0; i < 8; ++i)
#pragma unroll
        for (int j = 0; j < 4; ++j) acc[i][j] = 0.f;

    for (int q = 0; q < 4; ++q) {            // K quarters of 64
        const int k0 = q * 64;
        __syncthreads();
#pragma unroll
        for (int i = 0; i < 4; ++i) {        // A tile: 1024 float4s
            int f = i * 256 + t;
            int r = f >> 4, c = (f & 15) * 4;
            int gr = min(row0 + r, Mreal - 1);
            *(float4*)&As[r][c] = *(const float4*)&A[(size_t)gr * IN_DIM + k0 + c];
        }
#pragma unroll
        for (int i = 0; i < 8; ++i) {        // B tile: 2048 float4s
            int f = i * 256 + t;
            int r = f >> 5, c = (f & 31) * 4;
            *(float4*)&Bs[r][c] = *(const float4*)&B[(k0 + r) * HID + c];
        }
        __syncthreads();
#pragma unroll 4
        for (int k = 0; k < 64; ++k) {
            float4 bv = *(float4*)&Bs[k][cg * 4];   // contiguous 512B/wave: conflict-free
#pragma unroll
            for (int i = 0; i < 8; ++i) {
                float av = As[rg * 8 + i][k];
                acc[i][0] += av * bv.x; acc[i][1] += av * bv.y;
                acc[i][2] += av * bv.z; acc[i][3] += av * bv.w;
            }
        }
    }
#pragma unroll
    for (int i = 0; i < 8; ++i) {
        const int r = row0 + rg * 8 + i;
        const bool valid = (r < Mreal);
        unsigned short h[4], l[4];
#pragma unroll
        for (int j = 0; j < 4; ++j) {
            float x = valid ? acc[i][j] : 0.f;
            unsigned short hh = f2bf(x);
            h[j] = hh;
            l[j] = f2bf(x - bf2f(hh));
        }
        if (dest) {
            uint2 v; v.x = (u32)h[0] | ((u32)h[1] << 16); v.y = (u32)h[2] | ((u32)h[3] << 16);
            *(uint2*)&g2b[(size_t)r * HID + cg * 4] = v;   // r < 10240 always
        } else {
            uint2 vh; vh.x = (u32)h[0] | ((u32)h[1] << 16); vh.y = (u32)h[2] | ((u32)h[3] << 16);
            uint2 vl; vl.x = (u32)l[0] | ((u32)l[1] << 16); vl.y = (u32)l[2] | ((u32)l[3] << 16);
            *(uint2*)&h1h[(size_t)r * HID + cg * 4] = vh;
            *(uint2*)&h1l[(size_t)r * HID + cg * 4] = vl;
        }
    }
}

// ---------------- D: fused e = g2 @ h1^T, lrelu, mask, exp, row partials ----------------
// grid = (NCHUNKS, MBLKS), 256 threads (4 waves). Wave strip: 64 rows x 64 cols/iter.
// A (g2, pre-scaled by SCALE*log2e) plain bf16 in registers; B (h1) hi/lo bf16 in LDS.
// No online max: scores bounded, softmax is shift-invariant.
__global__ __launch_bounds__(256, 2)
void attn_kernel(const float* __restrict__ bias, const unsigned short* __restrict__ g2b,
                 const unsigned short* __restrict__ h1h, const unsigned short* __restrict__ h1l,
                 const float* __restrict__ ftc, const float* __restrict__ okf,
                 float* __restrict__ sumb, float* __restrict__ accb) {
    __shared__ char Bsh[2][16384];   // [half][col 64 x 256B swizzled]
    __shared__ float fts[NCHUNK];
    __shared__ float oks[NCHUNK];
    const int t = threadIdx.x;
    const int w = t >> 6, l = t & 63;
    const int m15 = l & 15, g = l >> 4;
    const int chunk = blockIdx.x, mblk = blockIdx.y;
    const int mrow0 = mblk * BM + w * 64;
    const int jc0 = chunk * NCHUNK;

    for (int i = t; i < NCHUNK; i += 256) { fts[i] = ftc[jc0 + i]; oks[i] = okf[jc0 + i]; }

    // A fragments: 16 x (8 bf16), resident for the whole kernel
    s16x8 afr[4][4];
#pragma unroll
    for (int mf = 0; mf < 4; ++mf)
#pragma unroll
        for (int ka = 0; ka < 4; ++ka) {
            const int row = mrow0 + 16 * mf + m15;       // < MPAD (zero-padded)
            afr[mf][ka] = *(const s16x8*)(g2b + (size_t)row * HID + ka * 32 + g * 8);
        }

    // per-lane swizzled k-offsets for B-frag ds_reads
    int tk[4];
#pragma unroll
    for (int ka = 0; ka < 4; ++ka) tk[ka] = ((ka * 64 + g * 16) ^ ((m15 & 7) << 4));

    float ps[16], pa[16];
#pragma unroll
    for (int s = 0; s < 16; ++s) { ps[s] = 0.f; pa[s] = 0.f; }

    for (int it = 0; it < 5; ++it) {
        const int j0 = jc0 + it * NTILE;
        __syncthreads();                     // previous tile fully consumed
        // stage h1 hi/lo tile (64 cols x 128 k), XOR-swizzled at ds_write
#pragma unroll
        for (int i = 0; i < 4; ++i) {
            int id = t + 256 * i;            // 16B-block id, < 1024
            int c = id >> 4, q = id & 15;
            uint4 vh = *(const uint4*)(h1h + (size_t)(j0 + c) * HID + q * 8);
            uint4 vl = *(const uint4*)(h1l + (size_t)(j0 + c) * HID + q * 8);
            int dst = c * 256 + ((q * 16) ^ ((c & 7) << 4));
            *(uint4*)&Bsh[0][dst] = vh;
            *(uint4*)&Bsh[1][dst] = vl;
        }
        __syncthreads();

        // bias loads for the whole iter, issued early (latency hidden under MFMA)
        float bv[4][4][4];
#pragma unroll
        for (int mf = 0; mf < 4; ++mf)
#pragma unroll
            for (int ri = 0; ri < 4; ++ri) {
                int row = mrow0 + 16 * mf + 4 * g + ri;
                row = min(row, N_DEST - 1);              // pad rows read row 9999 (discarded)
                const u32 rb = (u32)row * (u32)N_SRC;
#pragma unroll
                for (int nf = 0; nf < 4; ++nf) {
                    bv[mf][ri][nf] = __builtin_nontemporal_load(&bias[rb + (u32)(j0 + 16 * nf + m15)]);
                }
            }

#pragma unroll
        for (int nf = 0; nf < 4; ++nf) {
            s16x8 bh[4], bl[4];
#pragma unroll
            for (int ka = 0; ka < 4; ++ka) {
                int off = (nf * 16 + m15) * 256 + tk[ka];
                bh[ka] = *(const s16x8*)&Bsh[0][off];
                bl[ka] = *(const s16x8*)&Bsh[1][off];
            }
            const float ftv = fts[it * 64 + nf * 16 + m15];
            const float okv = oks[it * 64 + nf * 16 + m15];
#pragma unroll
            for (int mf = 0; mf < 4; ++mf) {
                f32x4 acc = { 0.f, 0.f, 0.f, 0.f };
#pragma unroll
                for (int ka = 0; ka < 4; ++ka) {
                    acc = __builtin_amdgcn_mfma_f32_16x16x32_bf16(afr[mf][ka], bh[ka], acc, 0, 0, 0);
                    acc = __builtin_amdgcn_mfma_f32_16x16x32_bf16(afr[mf][ka], bl[ka], acc, 0, 0, 0);
                }
#pragma unroll
                for (int ri = 0; ri < 4; ++ri) {
                    float s = acc[ri];
                    s = fmaxf(s, LRS * s);                       // lrelu (scale+log2e pre-folded)
                    float keep = (bv[mf][ri][nf] > 0.0f) ? okv : 0.0f;
                    float p = __builtin_amdgcn_exp2f(s) * keep;  // 2^s; masked -> 0
                    ps[mf * 4 + ri] += p;
                    pa[mf * 4 + ri] += p * ftv;
                }
            }
        }
    }

    // reduce each row partial across its 16-lane group, then one atomic per row
#pragma unroll
    for (int s = 0; s < 16; ++s) {
        float a = ps[s], b = pa[s];
#pragma unroll
        for (int m = 1; m < 16; m <<= 1) {
            a += __shfl_xor(a, m, 64);
            b += __shfl_xor(b, m, 64);
        }
        if (m15 == 0) {
            int row = mrow0 + 16 * (s >> 2) + 4 * g + (s & 3);
            if (row < N_DEST) {
                atomicAdd(&sumb[row], a);
                atomicAdd(&accb[row], b);
            }
        }
    }
}

// ---------------- F: out = acc / sum ----------------
__global__ void fin_kernel(const float* __restrict__ sumb, const float* __restrict__ accb,
                           float* __restrict__ out) {
    int i = blockIdx.x * 256 + threadIdx.x;
    if (i < N_DEST) out[i] = accb[i] / sumb[i];
}

extern "C" void kernel_launch(void* const* d_in, const int* in_sizes, int n_in,
                              void* d_out, int out_size, void* d_ws, size_t ws_size,
                              hipStream_t stream) {
    const float* bias     = (const float*)d_in[0];
    const float* emb_dest = (const float*)d_in[1];
    const float* emb_src  = (const float*)d_in[2];
    const float* ftr      = (const float*)d_in[3];
    const float* W        = (const float*)d_in[4];
    const float* W2       = (const float*)d_in[5];
    float* out = (float*)d_out;

    char* ws = (char*)d_ws;
    size_t off = 0;
    auto alloc = [&](size_t bytes) -> void* {
        void* p = ws + off;
        off += (bytes + 255) & ~(size_t)255;
        return p;
    };
    float* Wc           = (float*)alloc(256 * 128 * 4);
    unsigned short* g2b = (unsigned short*)alloc((size_t)MPAD * HID * 2);
    unsigned short* h1h = (unsigned short*)alloc((size_t)N_SRC * HID * 2);
    unsigned short* h1l = (unsigned short*)alloc((size_t)N_SRC * HID * 2);
    float* ftc          = (float*)alloc(N_SRC * 4);
    float* okf          = (float*)alloc(N_SRC * 4);
    float* sumb         = (float*)alloc(MPAD * 4);
    float* accb         = (float*)alloc(MPAD * 4);
    (void)ws_size; (void)in_sizes; (void)n_in; (void)out_size;

    prep_kernel<<<MPAD / 256, 256, 0, stream>>>(ftr, ftc, okf, sumb, accb);
    wc_kernel<<<16, 256, 0, stream>>>(W, W2, Wc);
    proj2_kernel<<<285, 256, 0, stream>>>(emb_dest, emb_src, Wc, W, g2b, h1h, h1l);
    attn_kernel<<<dim3(NCHUNKS, MBLKS), 256, 0, stream>>>(bias, g2b, h1h, h1l, ftc, okf, sumb, accb);
    fin_kernel<<<MPAD / 256, 256, 0, stream>>>(sumb, accb, out);
}